// Round 1
// baseline (159.863 us; speedup 1.0000x reference)
//
#include <hip/hip_runtime.h>
#include <hip/hip_bf16.h>

// IsometricLoss: loss = (1/N) * sum_{i,m} r[i,m] * max(||X_i||^2 + ||mu_m||^2 - 2 X_i.mu_m, 0)
// N=131072, M=128, D=128, fp32 in, fp32 scalar out.
// Strategy: bf16 MFMA for the cross term (memory-bound otherwise fp32 VALU-bound),
// exact fp32 x2/mu2, direct coalesced r loads matched to the MFMA C/D layout.

typedef __attribute__((ext_vector_type(8)))  short  short8;   // 8 bf16 = 4 VGPRs (MFMA A/B frag)
typedef __attribute__((ext_vector_type(16))) float  float16v; // MFMA 32x32 accumulator

__device__ __forceinline__ unsigned short f32_bf16(float f) {
    // round-to-nearest-even fp32 -> bf16 (inputs are finite normals)
    unsigned int u = __float_as_uint(f);
    u += 0x7fffu + ((u >> 16) & 1u);
    return (unsigned short)(u >> 16);
}

__global__ void zero_out_kernel(float* out) { out[0] = 0.0f; }

__global__ __launch_bounds__(256, 4)
void isoloss_kernel(const float* __restrict__ X,
                    const float* __restrict__ r,
                    const float* __restrict__ mus,
                    float* __restrict__ out)
{
    const int tid  = threadIdx.x;
    const int wave = tid >> 6;    // 0..3 -> which 32-mu tile this wave owns
    const int lane = tid & 63;
    const int col  = lane & 31;   // MFMA n-index (mu within tile) / m-index (row within tile)
    const int half = lane >> 5;   // 0/1

    __shared__ unsigned short ldsA[32][136]; // X tile bf16, pad 128->136 (16B-aligned, 4-way bank alias only)
    __shared__ float x2s[32];
    __shared__ float wsum[4];

    // ---- preload B fragments (this wave's 32 mus) into registers + exact fp32 mu2 ----
    // B layout for 32x32x16: lane holds B[k=(lane>>5)*8+j][n=lane&31]; we want B[k][n]=mus[n][k],
    // so lane reads mus[col][ks*16 + half*8 + j], j=0..7.
    short8 bfrag[8];
    float mu2p = 0.0f;
    {
        const float* mrow = mus + (size_t)(wave * 32 + col) * 128;
        #pragma unroll
        for (int ks = 0; ks < 8; ++ks) {
            const float4 a = *(const float4*)(mrow + ks * 16 + half * 8);
            const float4 b = *(const float4*)(mrow + ks * 16 + half * 8 + 4);
            mu2p += a.x*a.x + a.y*a.y + a.z*a.z + a.w*a.w
                  + b.x*b.x + b.y*b.y + b.z*b.z + b.w*b.w;
            short8 f;
            f[0] = (short)f32_bf16(a.x); f[1] = (short)f32_bf16(a.y);
            f[2] = (short)f32_bf16(a.z); f[3] = (short)f32_bf16(a.w);
            f[4] = (short)f32_bf16(b.x); f[5] = (short)f32_bf16(b.y);
            f[6] = (short)f32_bf16(b.z); f[7] = (short)f32_bf16(b.w);
            bfrag[ks] = f;
        }
    }
    // each lane covers half the k-range for its mu; combine halves -> exact mu2[col]
    const float mu2 = mu2p + __shfl_xor(mu2p, 32);

    float s = 0.0f;

    const int row_stage = tid >> 3;      // 32 rows, 8 threads/row
    const int c0        = (tid & 7) * 4; // float4 column base within row

    for (int g = blockIdx.x; g < 4096; g += gridDim.x) {
        const int rowbase = g * 32;

        __syncthreads();  // previous iteration's LDS consumers done before overwrite

        // ---- stage X[32x128] fp32 -> bf16 LDS, exact fp32 x2 along the way ----
        {
            const float* xrow = X + (size_t)(rowbase + row_stage) * 128;
            float p = 0.0f;
            #pragma unroll
            for (int j = 0; j < 4; ++j) {
                const float4 v = *(const float4*)(xrow + c0 + j * 32);
                p += v.x*v.x + v.y*v.y + v.z*v.z + v.w*v.w;
                ushort4 h;
                h.x = f32_bf16(v.x); h.y = f32_bf16(v.y);
                h.z = f32_bf16(v.z); h.w = f32_bf16(v.w);
                *(ushort4*)&ldsA[row_stage][c0 + j * 32] = h;
            }
            // 8 threads (consecutive lanes) share one row: tree-reduce
            p += __shfl_down(p, 4);
            p += __shfl_down(p, 2);
            p += __shfl_down(p, 1);
            if ((tid & 7) == 0) x2s[row_stage] = p;
        }
        __syncthreads();

        // ---- cross tile: 8 x mfma_32x32x16_bf16 over D=128 ----
        // A layout: lane holds A[m=lane&31][k=(lane>>5)*8+j] = X[rowbase+col][ks*16+half*8+j]
        float16v acc = {};
        #pragma unroll
        for (int ks = 0; ks < 8; ++ks) {
            const short8 af = *(const short8*)&ldsA[col][ks * 16 + half * 8];
            acc = __builtin_amdgcn_mfma_f32_32x32x16_bf16(af, bfrag[ks], acc, 0, 0, 0);
        }

        // ---- epilogue: D[row][col] with col=lane&31 (mu idx), row=(reg&3)+8*(reg>>2)+4*half ----
        // r loads: lanes 0..31 contiguous in m -> coalesced 128B segments.
        const float* rbase = r + (size_t)rowbase * 128 + wave * 32 + col;
        #pragma unroll
        for (int reg = 0; reg < 16; ++reg) {
            const int rl = (reg & 3) + 8 * (reg >> 2) + 4 * half;
            float d = x2s[rl] + mu2 - 2.0f * acc[reg];
            d = fmaxf(d, 0.0f);
            s += rbase[(size_t)rl * 128] * d;
        }
    }

    // ---- reduce: wave shuffle -> block -> one atomic ----
    #pragma unroll
    for (int off = 32; off > 0; off >>= 1) s += __shfl_down(s, off);
    if (lane == 0) wsum[wave] = s;
    __syncthreads();
    if (tid == 0) {
        const float t = wsum[0] + wsum[1] + wsum[2] + wsum[3];
        atomicAdd(out, t * (1.0f / 131072.0f));
    }
}

extern "C" void kernel_launch(void* const* d_in, const int* in_sizes, int n_in,
                              void* d_out, int out_size, void* d_ws, size_t ws_size,
                              hipStream_t stream) {
    const float* X   = (const float*)d_in[0];   // [131072, 128]
    const float* r   = (const float*)d_in[1];   // [131072, 128]
    const float* mus = (const float*)d_in[2];   // [128, 128]
    float* out = (float*)d_out;                 // scalar

    zero_out_kernel<<<1, 1, 0, stream>>>(out);  // d_out is poisoned 0xAA each call
    isoloss_kernel<<<1024, 256, 0, stream>>>(X, r, mus, out);
}